// Round 19
// baseline (406.566 us; speedup 1.0000x reference)
//
#include <hip/hip_runtime.h>
#include <hip/hip_fp16.h>
#include <cstdint>
#include <cstddef>

#define BATCH 8
#define TT 8192
#define HD 256
#define RTOT (BATCH * TT)   // 65536
#define HC 16               // half-chunk length
#define NPAIR (TT / (2 * HC)) // 256 workgroups, each owns 2 half-chunks

typedef __attribute__((ext_vector_type(4))) float    f32x4;
typedef __attribute__((ext_vector_type(8))) _Float16 f16x8;
typedef __attribute__((ext_vector_type(4))) _Float16 f16x4;

typedef __attribute__((address_space(1))) const void gvoid_t;
typedef __attribute__((address_space(3))) void lvoid_t;

__device__ __forceinline__ void gl_lds16(const void* g, void* l) {
  __builtin_amdgcn_global_load_lds((gvoid_t*)g, (lvoid_t*)l, 16, 0, 0);
}

// LDS-only barrier, DS-masked fence (R12-exact; scan only).
__device__ __forceinline__ void ldsbar() {
  asm volatile("s_waitcnt lgkmcnt(0)" ::: "memory");
  __builtin_amdgcn_s_barrier();
  __builtin_amdgcn_sched_barrier(0x7F);
}

// Fenced barrier for the GEMM k-loop (R11/R13-validated pattern).
__device__ __forceinline__ void gbar() {
  __builtin_amdgcn_s_barrier();
  __builtin_amdgcn_sched_barrier(0);
  asm volatile("" ::: "memory");
}

// ---------------------------------------------------------------------------
// Parallel start-flag dtype detection: bad[0]=not-int32, bad[1]=not-f32.
// ---------------------------------------------------------------------------
__global__ void detect_start_par(const unsigned int* __restrict__ s,
                                 int* __restrict__ bad) {
  const unsigned int w = s[blockIdx.x * blockDim.x + threadIdx.x];
  const unsigned int b0 = w & 255u, b1 = (w >> 8) & 255u,
                     b2 = (w >> 16) & 255u, b3 = (w >> 24) & 255u;
  const int bi = (b1 | b2 | b3) != 0;
  const int bf = (b0 != 0) || (b1 != 0) ||
                 (b2 != 0 && b2 != 0x80u) || (b3 != 0 && b3 != 0x3fu);
  if (__any(bi) && (threadIdx.x & 63) == 0) atomicOr(&bad[0], 1);
  if (__any(bf) && (threadIdx.x & 63) == 0) atomicOr(&bad[1], 1);
}

// ---------------------------------------------------------------------------
// f32 -> f16 conversion, vectorized.
// ---------------------------------------------------------------------------
__global__ void conv_f16(const float* __restrict__ in, _Float16* __restrict__ out,
                         const int n) {
  const int i = (blockIdx.x * blockDim.x + threadIdx.x) * 8;
  if (i + 7 >= n) return;
  const float4 a = *(const float4*)&in[i];
  const float4 b = *(const float4*)&in[i + 4];
  f16x8 v;
  v[0] = (_Float16)a.x; v[1] = (_Float16)a.y; v[2] = (_Float16)a.z; v[3] = (_Float16)a.w;
  v[4] = (_Float16)b.x; v[5] = (_Float16)b.y; v[6] = (_Float16)b.z; v[7] = (_Float16)b.w;
  *(f16x8*)&out[i] = v;
}

__global__ void conv_w8(const float* p0, const float* p1, const float* p2,
                        const float* p3, const float* p4, const float* p5,
                        const float* p6, const float* p7,
                        _Float16* __restrict__ out) {
  const int seg = blockIdx.y;
  const float* p;
  switch (seg) {
    case 0: p = p0; break; case 1: p = p1; break;
    case 2: p = p2; break; case 3: p = p3; break;
    case 4: p = p4; break; case 5: p = p5; break;
    case 6: p = p6; break; default: p = p7; break;
  }
  const int i = (blockIdx.x * blockDim.x + threadIdx.x) * 8;
  const float4 a = *(const float4*)&p[i];
  const float4 b = *(const float4*)&p[i + 4];
  f16x8 v;
  v[0] = (_Float16)a.x; v[1] = (_Float16)a.y; v[2] = (_Float16)a.z; v[3] = (_Float16)a.w;
  v[4] = (_Float16)b.x; v[5] = (_Float16)b.y; v[6] = (_Float16)b.z; v[7] = (_Float16)b.w;
  *(f16x8*)&out[(size_t)seg * 65536 + i] = v;
}

// ---------------------------------------------------------------------------
// Pre-swizzle Uf/Uh (both layers) into per-lane MFMA fragment order, fp16.
// ---------------------------------------------------------------------------
__global__ void swz_w(const float* __restrict__ Uf, const float* __restrict__ Uh,
                      _Float16* __restrict__ outp) {
  const int gid  = blockIdx.x * 256 + threadIdx.x;   // 32768 total
  const int lane = gid & 63;
  const int w    = (gid >> 6) & 7;
  const int f    = (gid >> 9) & 15;
  const int mat  = (gid >> 13) & 1;
  const int l    = gid >> 14;
  const int fr = lane & 15, fq = lane >> 4;
  const int tile = f >> 3, kc = f & 7;
  const int nrow = (w * 2 + tile) * 16 + fr;
  const int kb   = kc * 32 + fq * 8;
  const float* src = (mat ? Uh : Uf) + (size_t)l * 65536 + nrow * 256 + kb;
  const float4 a = *(const float4*)src;
  const float4 b = *(const float4*)(src + 4);
  f16x8 v;
  v[0] = (_Float16)a.x; v[1] = (_Float16)a.y; v[2] = (_Float16)a.z; v[3] = (_Float16)a.w;
  v[4] = (_Float16)b.x; v[5] = (_Float16)b.y; v[6] = (_Float16)b.z; v[7] = (_Float16)b.w;
  *(f16x8*)&outp[(size_t)gid * 8] = v;
}

// ---------------------------------------------------------------------------
// FUSED boundary GEMM (R16 structure). Dual-output case stores into the
// scan's P-LAYOUT buffer xP: element (b,t,n,mat) at
//   ((slot(t)*512 + (n>>5)*64 + ((n>>2)&3)*16 + grp(t)*8 + b)*16
//     + mat*8 + ((n>>4)&1)*4 + (n&3))
// slot(t) = (t>>5)*16 + (t&15), grp(t) = (t>>4)&1. This makes the scan's
// per-step loads 2x fully-coalesced 16B/lane (was 4x scattered 8B/lane).
// Single-output (C32) path unchanged.
// ---------------------------------------------------------------------------
__global__ __launch_bounds__(256, 2) void gemm_fused(
    const _Float16* __restrict__ A,
    const _Float16* __restrict__ W1, const float* __restrict__ b1, const int act1,
    const _Float16* __restrict__ Wa, const float* __restrict__ ba,
    const _Float16* __restrict__ Wb, const float* __restrict__ bb,
    _Float16* __restrict__ xP,
    float* __restrict__ C32) {
  __shared__ __align__(16) char smem[65536];
  char* Amid = smem;                 // 32KB: A tile, then mid (swizzled)
  char* stg  = smem + 32768;         // 2 x 16KB W double-buffer

  const int tid  = threadIdx.x;
  const int wave = tid >> 6, lane = tid & 63;
  const int wm = wave >> 1, wn = wave & 1;
  const int bm = blockIdx.x * 64;
  const int lrow  = tid >> 2;        // 0..63
  const int lcol8 = (tid & 3) * 8;
  const int fr = lane & 15;
  const int fq = lane >> 4;

  auto ldswz = [&](int row, int colbyte) -> const f16x8* {
    return (const f16x8*)(Amid + row * 512 + (colbyte ^ ((row & 15) << 4)));
  };

  // ---- stage A once (swizzled source -> linear dest) ----
#pragma unroll
  for (int it = 0; it < 8; it++) {
    const int o   = (it * 256 + tid) * 16;
    const int row = o >> 9;
    const int cb  = (o & 511) ^ ((row & 15) << 4);
    gl_lds16(&A[(size_t)(bm + row) * HD + (cb >> 1)], Amid + o);
  }

  auto STW = [&](const _Float16* W, int kk, int b2) {  // 16KB tile, 4 ld/thr
    const int k0 = kk * 32;
#pragma unroll
    for (int is = 0; is < 4; is++)
      gl_lds16(&W[(size_t)(is * 64 + lrow) * HD + k0 + lcol8],
               stg + b2 * 16384 + is * 4096 + wave * 1024);
  };

  // ================= phase A: mid = act1(A @ W1^T + b1) =================
  {
    f32x4 acc[2][8];
#pragma unroll
    for (int i = 0; i < 2; i++)
#pragma unroll
      for (int j = 0; j < 8; j++) acc[i][j] = (f32x4){0.f, 0.f, 0.f, 0.f};

    STW(W1, 0, 0);
#pragma unroll
    for (int k = 0; k < 8; k++) {
      const int cur = k & 1;
      if (k < 7) {
        STW(W1, k + 1, cur ^ 1);
        asm volatile("s_waitcnt vmcnt(4)" ::: "memory");
      } else {
        asm volatile("s_waitcnt vmcnt(0)" ::: "memory");
      }
      gbar();
      const _Float16* Ws = (const _Float16*)(stg + cur * 16384);
      f16x8 af[2], bf[8];
#pragma unroll
      for (int mi = 0; mi < 2; mi++)
        af[mi] = *ldswz(wm * 32 + mi * 16 + fr, k * 64 + fq * 16);
#pragma unroll
      for (int ni = 0; ni < 8; ni++)
        bf[ni] = *(const f16x8*)(Ws + (wn * 128 + ni * 16 + fr) * 32 + fq * 8);
#pragma unroll
      for (int mi = 0; mi < 2; mi++)
#pragma unroll
        for (int ni = 0; ni < 8; ni++)
          acc[mi][ni] = __builtin_amdgcn_mfma_f32_16x16x32_f16(af[mi], bf[ni],
                                                               acc[mi][ni], 0, 0, 0);
      asm volatile("s_waitcnt lgkmcnt(0)" ::: "memory");
      gbar();
    }
    __syncthreads();   // all waves done reading A
    // epilogue: bias (+leaky) -> fp16 -> mid (overlays A, same swizzle)
#pragma unroll
    for (int mi = 0; mi < 2; mi++)
#pragma unroll
      for (int ni = 0; ni < 8; ni++) {
        const float bvv = b1[wn * 128 + ni * 16 + fr];
#pragma unroll
        for (int j = 0; j < 4; j++) {
          float v = acc[mi][ni][j] + bvv;
          if (act1 == 1) v = (v > 0.f) ? v : 0.01f * v;
          const int row = wm * 32 + mi * 16 + fq * 4 + j;
          const int cb  = ((wn * 128 + ni * 16 + fr) * 2) ^ ((row & 15) << 4);
          *(_Float16*)(Amid + row * 512 + cb) = (_Float16)v;
        }
      }
  }
  __syncthreads();  // mid complete & visible

  // ============== phase B: C = mid @ Wm^T + bm, per mat ==============
  const int nmat = (Wb != nullptr) ? 2 : 1;
  for (int mat = 0; mat < nmat; mat++) {
    const _Float16* W2 = mat ? Wb : Wa;
    const float* b2p   = mat ? bb : ba;

    f32x4 acc[2][8];
#pragma unroll
    for (int i = 0; i < 2; i++)
#pragma unroll
      for (int j = 0; j < 8; j++) acc[i][j] = (f32x4){0.f, 0.f, 0.f, 0.f};

    STW(W2, 0, 0);
#pragma unroll
    for (int k = 0; k < 8; k++) {
      const int cur = k & 1;
      if (k < 7) {
        STW(W2, k + 1, cur ^ 1);
        asm volatile("s_waitcnt vmcnt(4)" ::: "memory");
      } else {
        asm volatile("s_waitcnt vmcnt(0)" ::: "memory");
      }
      gbar();
      const _Float16* Ws = (const _Float16*)(stg + cur * 16384);
      f16x8 af[2], bf[8];
#pragma unroll
      for (int mi = 0; mi < 2; mi++)
        af[mi] = *ldswz(wm * 32 + mi * 16 + fr, k * 64 + fq * 16);
#pragma unroll
      for (int ni = 0; ni < 8; ni++)
        bf[ni] = *(const f16x8*)(Ws + (wn * 128 + ni * 16 + fr) * 32 + fq * 8);
#pragma unroll
      for (int mi = 0; mi < 2; mi++)
#pragma unroll
        for (int ni = 0; ni < 8; ni++)
          acc[mi][ni] = __builtin_amdgcn_mfma_f32_16x16x32_f16(af[mi], bf[ni],
                                                               acc[mi][ni], 0, 0, 0);
      asm volatile("s_waitcnt lgkmcnt(0)" ::: "memory");
      gbar();
    }

    // epilogue
    if (C32 != nullptr) {
      // final output: fp32 direct scatter (unchanged)
#pragma unroll
      for (int mi = 0; mi < 2; mi++)
#pragma unroll
        for (int ni = 0; ni < 8; ni++) {
          const float bvv = b2p[wn * 128 + ni * 16 + fr];
#pragma unroll
          for (int j = 0; j < 4; j++)
            C32[(size_t)(bm + wm * 32 + mi * 16 + fq * 4 + j) * HD +
                wn * 128 + ni * 16 + fr] = acc[mi][ni][j] + bvv;
        }
    } else {
      // P-layout scatter store for the scan
#pragma unroll
      for (int mi = 0; mi < 2; mi++)
#pragma unroll
        for (int ni = 0; ni < 8; ni++) {
          const int n   = wn * 128 + ni * 16 + fr;
          const float bvv = b2p[n];
          const int wv   = n >> 5;
          const int half = (n >> 4) & 1;
          const int fqs  = (n >> 2) & 3;
          const int js   = n & 3;
#pragma unroll
          for (int j = 0; j < 4; j++) {
            const int r   = bm + wm * 32 + mi * 16 + fq * 4 + j;
            const int t   = r & (TT - 1);
            const int bb2 = r >> 13;
            const int slot = ((t >> 5) << 4) | (t & 15);
            const int grp  = (t >> 4) & 1;
            const size_t e =
                (((size_t)slot * 512) + wv * 64 + fqs * 16 + grp * 8 + bb2) * 16 +
                mat * 8 + half * 4 + js;
            xP[e] = (_Float16)(acc[mi][ni][j] + bvv);
          }
        }
    }
    if (mat == 0 && nmat == 2) __syncthreads();  // stg reuse ordering
  }
}

// ---------------------------------------------------------------------------
// MGU scan — R12-frozen structure; ONLY the xf/xh load sites changed to the
// P-layout (2 coalesced 16B/lane loads per step instead of 4 scattered 8B).
// ---------------------------------------------------------------------------
__global__ __launch_bounds__(512) void scan_mgu(
    const _Float16* __restrict__ xP,
    const void* __restrict__ startp, const int* __restrict__ badf,
    const float* __restrict__ h0l,
    const _Float16* __restrict__ wfrag,
    _Float16* __restrict__ z, float* __restrict__ hfin,
    _Float16* __restrict__ dumpz) {
  const int tid  = threadIdx.x;
  const int wave = tid >> 6;
  const int lane = tid & 63;
  const int fr   = lane & 15;      // MFMA col / frag row
  const int fq   = lane >> 4;      // 0..3
  const int col  = fr;
  const int b    = col & 7;
  const int grp  = col >> 3;       // 0 = half-chunk A, 1 = B
  const int base = blockIdx.x * (2 * HC);
  const int t0c  = base + grp * HC;
  const int mode = (!badf[0]) ? 1 : (!badf[1] ? 2 : 0);

  __shared__ __align__(16) char hbuf[8192];  // frag layout [kc][krow][col][8]
  __shared__ __align__(16) char gbuf[8192];
  __shared__ int rb[16];

  _Float16* dp0 = dumpz + ((size_t)blockIdx.x * 512 + tid) * 16;

  auto flag = [&](int bb, int t) -> int {
    const int idx = bb * TT + t;
    if (mode == 1) return ((const int*)startp)[idx] != 0;
    if (mode == 2) return ((const float*)startp)[idx] != 0.0f;
    return ((const uint8_t*)startp)[idx] != 0;
  };
  auto ldfrag = [&](const char* buf, int kc) -> f16x8 {
    int off = kc * 1024 + fq * 256 + fr * 16;
    off ^= ((off >> 8) & 1) << 4;
    return *(const f16x8*)(buf + off);
  };
  auto stfrag = [&](char* buf, int nb, const float4 v) {
    int off = ((nb >> 5) * 1024) + (((nb >> 3) & 3) * 256) + col * 16 + (nb & 7) * 2;
    off ^= ((off >> 8) & 1) << 4;
    f16x4 p;
    p[0] = (_Float16)v.x; p[1] = (_Float16)v.y;
    p[2] = (_Float16)v.z; p[3] = (_Float16)v.w;
    *(f16x4*)(buf + off) = p;
  };
  // P-layout step load: two coalesced 16B reads per lane.
  auto ldx = [&](int tc, f16x4& xf0, f16x4& xf1, f16x4& xh0, f16x4& xh1) {
    const int slot = ((tc >> 5) << 4) | (tc & 15);
    const int gT   = (tc >> 4) & 1;
    const _Float16* pp =
        &xP[(((size_t)slot * 512) + wave * 64 + fq * 16 + gT * 8 + b) * 16];
    const f16x8 vf = *(const f16x8*)pp;
    const f16x8 vh = *(const f16x8*)(pp + 8);
    xf0[0] = vf[0]; xf0[1] = vf[1]; xf0[2] = vf[2]; xf0[3] = vf[3];
    xf1[0] = vf[4]; xf1[1] = vf[5]; xf1[2] = vf[6]; xf1[3] = vf[7];
    xh0[0] = vh[0]; xh0[1] = vh[1]; xh0[2] = vh[2]; xh0[3] = vh[3];
    xh1[0] = vh[4]; xh1[1] = vh[5]; xh1[2] = vh[6]; xh1[3] = vh[7];
  };

  // ---- weight fragments: 32 coalesced dwordx4 per lane from swz buffer ----
  f16x8 auf[2][8], auh[2][8];
#pragma unroll
  for (int f = 0; f < 16; f++)
    auf[f >> 3][f & 7] =
        *(const f16x8*)&wfrag[((size_t)(f * 512) + wave * 64 + lane) * 8];
#pragma unroll
  for (int f = 0; f < 16; f++)
    auh[f >> 3][f & 7] =
        *(const f16x8*)&wfrag[((size_t)(8192 + f * 512) + wave * 64 + lane) * 8];

  // ---- per-column lookback: last reset <= t0c (or -1) ----
  if (tid < 16) rb[tid] = -1;
  __syncthreads();
  {
    const int cg  = tid >> 5;            // 16 groups x 32 threads
    const int l32 = tid & 31;
    const int t0g = base + (cg >> 3) * HC;
    const int bg  = cg & 7;
    for (int off = 0;; off += 32) {
      const int st = t0g - off - l32;
      if (st >= 0 && rb[cg] < 0 && flag(bg, st)) atomicMax(&rb[cg], st);
      __syncthreads();
      bool done = true;
#pragma unroll
      for (int c = 0; c < 16; c++) {
        const int tc = base + (c >> 3) * HC;
        if (rb[c] < 0 && tc - off >= 0) done = false;
      }
      if (done) break;
      __syncthreads();
    }
  }
  __syncthreads();

  const int rbc    = rb[col];
  const int startc = max(rbc, 0);
  int Lmax = 0;
#pragma unroll
  for (int c = 0; c < 16; c++) {
    const int tc = base + (c >> 3) * HC;
    const int s  = max(rb[c], 0);
    Lmax = max(Lmax, tc - s);
  }

  const int nb0 = (wave * 2 + 0) * 16 + fq * 4;
  const int nb1 = (wave * 2 + 1) * 16 + fq * 4;

  // ---- init carry (registers, D-layout) ----
  float4 hinit0 = make_float4(0.f, 0.f, 0.f, 0.f), hinit1 = hinit0;
  if (rbc < 0) {
    hinit0 = *(const float4*)&h0l[b * HD + nb0];
    hinit1 = *(const float4*)&h0l[b * HD + nb1];
  }
  float4 hr0 = hinit0, hr1 = hinit1;
  stfrag(hbuf, nb0, hr0);
  stfrag(hbuf, nb1, hr1);
  __syncthreads();

  // ---- prefetch first step (P-layout + fold flag; unconditional-clamped) --
  int t = t0c - Lmax;
  int tcl = min(max(t, 0), TT - 1);
  f16x4 pxf0, pxf1, pxh0, pxh1;
  ldx(tcl, pxf0, pxf1, pxh0, pxh1);
  int fnext;
  {
    const int ftn = flag(b, min(max(t + 1, 0), TT - 1));
    fnext = (t + 1 < TT) ? ftn : 0;
  }

  for (int i = -Lmax; i < HC; i++) {
    t = t0c + i;
    f32x4 cf0 = {(float)pxf0[0], (float)pxf0[1], (float)pxf0[2], (float)pxf0[3]};
    f32x4 cf1 = {(float)pxf1[0], (float)pxf1[1], (float)pxf1[2], (float)pxf1[3]};
    f32x4 ch0 = {(float)pxh0[0], (float)pxh0[1], (float)pxh0[2], (float)pxh0[3]};
    f32x4 ch1 = {(float)pxh1[0], (float)pxh1[1], (float)pxh1[2], (float)pxh1[3]};

    const int fcur = fnext;                      // flag(b, t+1)
    const int tn = min(max(t + 1, 0), TT - 1);
    ldx(tn, pxf0, pxf1, pxh0, pxh1);
    {
      const int ftn = flag(b, min(max(t + 2, 0), TT - 1));
      fnext = (t + 2 < TT) ? ftn : 0;
    }

    // carry-fold selector for next step: 2=freeze to init, 1=zero, 0=keep
    int stn = 0;
    if (t + 1 <= startc) stn = 2;
    else if (fcur) stn = 1;

    // matvec1: pre_f = Uf . h + xf
#pragma unroll
    for (int kc = 0; kc < 8; kc++) {
      const f16x8 bv = ldfrag(hbuf, kc);
      cf0 = __builtin_amdgcn_mfma_f32_16x16x32_f16(auf[0][kc], bv, cf0, 0, 0, 0);
      cf1 = __builtin_amdgcn_mfma_f32_16x16x32_f16(auf[1][kc], bv, cf1, 0, 0, 0);
    }
    // sigmoid, g = f*h
    f32x4 fv0, fv1;
    float4 g0, g1;
#pragma unroll
    for (int r = 0; r < 4; r++) {
      const float f0 = 1.f / (1.f + __expf(-cf0[r]));
      const float f1 = 1.f / (1.f + __expf(-cf1[r]));
      fv0[r] = f0; fv1[r] = f1;
      (&g0.x)[r] = f0 * (&hr0.x)[r];
      (&g1.x)[r] = f1 * (&hr1.x)[r];
    }
    stfrag(gbuf, nb0, g0);
    stfrag(gbuf, nb1, g1);
    ldsbar();

    // matvec2: pre_h = Uh . (f*h) + xh
#pragma unroll
    for (int kc = 0; kc < 8; kc++) {
      const f16x8 bv = ldfrag(gbuf, kc);
      ch0 = __builtin_amdgcn_mfma_f32_16x16x32_f16(auh[0][kc], bv, ch0, 0, 0, 0);
      ch1 = __builtin_amdgcn_mfma_f32_16x16x32_f16(auh[1][kc], bv, ch1, 0, 0, 0);
    }
    // update
    float4 hn0, hn1;
    f16x4 zn0, zn1;
#pragma unroll
    for (int r = 0; r < 4; r++) {
      const float e0 = __expf(2.f * ch0[r]);
      const float e1 = __expf(2.f * ch1[r]);
      const float hh0 = 1.f - 2.f / (e0 + 1.f);
      const float hh1 = 1.f - 2.f / (e1 + 1.f);
      (&hn0.x)[r] = (1.f - fv0[r]) * (&hr0.x)[r] + fv0[r] * hh0;
      (&hn1.x)[r] = (1.f - fv1[r]) * (&hr1.x)[r] + fv1[r] * hh1;
      zn0[r] = (_Float16)(&hn0.x)[r];
      zn1[r] = (_Float16)(&hn1.x)[r];
    }
    // z-store: ALWAYS issue; address selects real z vs per-thread dump slot.
    {
      const size_t tz = (size_t)b * TT + (size_t)max(t, 0);
      _Float16* zp0 = (i >= 0) ? &z[tz * HD + nb0] : dp0;
      _Float16* zp1 = (i >= 0) ? &z[tz * HD + nb1] : dp0 + 8;
      *(f16x4*)zp0 = zn0;
      *(f16x4*)zp1 = zn1;
    }
    // fold
    hr0 = (stn == 2) ? hinit0 : (stn == 1 ? make_float4(0.f, 0.f, 0.f, 0.f) : hn0);
    hr1 = (stn == 2) ? hinit1 : (stn == 1 ? make_float4(0.f, 0.f, 0.f, 0.f) : hn1);
    stfrag(hbuf, nb0, hr0);
    stfrag(hbuf, nb1, hr1);
    ldsbar();
  }

  // hfin: after the final step's fold (fcur=0, stn=0 at t=TT-1), hr == hn(TT-1)
  if (t0c + HC == TT) {
    *(float4*)&hfin[b * HD + nb0] = hr0;
    *(float4*)&hfin[b * HD + nb1] = hr1;
  }
}

// ---------------------------------------------------------------------------
extern "C" void kernel_launch(void* const* d_in, const int* in_sizes, int n_in,
                              void* d_out, int out_size, void* d_ws, size_t ws_size,
                              hipStream_t stream) {
  const float* emb    = (const float*)d_in[0];
  const void*  startp = d_in[1];
  const float* h0     = (const float*)d_in[2];
  const float* min_w  = (const float*)d_in[3];
  const float* min_b  = (const float*)d_in[4];
  const float* mout_w = (const float*)d_in[5];
  const float* mout_b = (const float*)d_in[6];
  const float* Wf_w   = (const float*)d_in[7];
  const float* Wf_b   = (const float*)d_in[8];
  const float* Wh_w   = (const float*)d_in[9];
  const float* Wh_b   = (const float*)d_in[10];
  const float* Uf_w   = (const float*)d_in[11];
  const float* Uh_w   = (const float*)d_in[12];
  const float* ff_w   = (const float*)d_in[13];
  const float* ff_b   = (const float*)d_in[14];

  float* out = (float*)d_out;
  char*  ws  = (char*)d_ws;
  int*   bad = (int*)ws;
  _Float16* w16  = (_Float16*)(ws + 1024);                         // 1 MB
  _Float16* uswz = (_Float16*)(ws + 1024 + 1048576);               // 512 KB
  _Float16* dump = (_Float16*)(ws + 1024 + 1048576 + 524288);      // 4 MB
  _Float16* bufE = (_Float16*)(ws + 1024 + 1048576 + 524288 + 4194304);  // 32 MB
  _Float16* bufA = bufE + (size_t)RTOT * HD;                        // 32 MB (z)
  _Float16* xP   = bufA + (size_t)RTOT * HD;                        // 64 MB
  float* hfin = out + (size_t)RTOT * HD;
  const size_t WO = (size_t)HD * HD;

  _Float16* w_min = w16;
  _Float16* w_out = w16 + 1 * WO;
  _Float16* w_f0  = w16 + 2 * WO;
  _Float16* w_f1  = w16 + 3 * WO;
  _Float16* w_h0  = w16 + 4 * WO;
  _Float16* w_h1  = w16 + 5 * WO;
  _Float16* w_ff0 = w16 + 6 * WO;
  _Float16* w_ff1 = w16 + 7 * WO;

  hipMemsetAsync(bad, 0, 16, stream);
  detect_start_par<<<64, 256, 0, stream>>>((const unsigned int*)startp, bad);
  conv_f16<<<RTOT * HD / 2048, 256, 0, stream>>>(emb, bufE, RTOT * HD);
  conv_w8<<<dim3(32, 8), 256, 0, stream>>>(min_w, mout_w, Wf_w, Wf_w + WO,
                                           Wh_w, Wh_w + WO, ff_w, ff_w + WO, w16);
  swz_w<<<128, 256, 0, stream>>>(Uf_w, Uh_w, uswz);

  // fused0: x0 = emb@min (internal) -> xP (xf0,xh0 in P-layout)
  gemm_fused<<<RTOT / 64, 256, 0, stream>>>(bufE, w_min, min_b, 0,
                                            w_f0, Wf_b, w_h0, Wh_b,
                                            xP, nullptr);
  scan_mgu<<<NPAIR, 512, 0, stream>>>(xP, startp, bad, h0,
                                      uswz, bufA, hfin, dump);
  // fused1: x1 = leaky(z0@ff0) (internal) -> xP (xf1,xh1 in P-layout)
  gemm_fused<<<RTOT / 64, 256, 0, stream>>>(bufA, w_ff0, ff_b, 1,
                                            w_f1, Wf_b + HD, w_h1, Wh_b + HD,
                                            xP, nullptr);
  scan_mgu<<<NPAIR, 512, 0, stream>>>(xP, startp, bad, h0 + BATCH * HD,
                                      uswz + (size_t)16384 * 8, bufA,
                                      hfin + BATCH * HD, dump);
  // fused2: x2 = leaky(z1@ff1) (internal) -> out = x2@mout+b (fp32)
  gemm_fused<<<RTOT / 64, 256, 0, stream>>>(bufA, w_ff1, ff_b + HD, 1,
                                            w_out, mout_b, nullptr, nullptr,
                                            nullptr, out);
}

// Round 20
// 322.117 us; speedup vs baseline: 1.2622x; 1.2622x over previous
//
#include <hip/hip_runtime.h>
#include <hip/hip_fp16.h>
#include <cstdint>
#include <cstddef>

#define BATCH 8
#define TT 8192
#define HD 256
#define RTOT (BATCH * TT)   // 65536
#define HC 16               // half-chunk length
#define NPAIR (TT / (2 * HC)) // 256 workgroups, each owns 2 half-chunks
#define PLANE ((size_t)TT * 2048)  // f16 elems per xP mat-plane (32 MB)

typedef __attribute__((ext_vector_type(4))) float    f32x4;
typedef __attribute__((ext_vector_type(8))) _Float16 f16x8;
typedef __attribute__((ext_vector_type(4))) _Float16 f16x4;

typedef __attribute__((address_space(1))) const void gvoid_t;
typedef __attribute__((address_space(3))) void lvoid_t;

__device__ __forceinline__ void gl_lds16(const void* g, void* l) {
  __builtin_amdgcn_global_load_lds((gvoid_t*)g, (lvoid_t*)l, 16, 0, 0);
}

// LDS-only barrier, DS-masked fence (R12-exact; scan only).
__device__ __forceinline__ void ldsbar() {
  asm volatile("s_waitcnt lgkmcnt(0)" ::: "memory");
  __builtin_amdgcn_s_barrier();
  __builtin_amdgcn_sched_barrier(0x7F);
}

// Fenced barrier for the GEMM k-loop (R11/R13-validated pattern).
__device__ __forceinline__ void gbar() {
  __builtin_amdgcn_s_barrier();
  __builtin_amdgcn_sched_barrier(0);
  asm volatile("" ::: "memory");
}

// ---------------------------------------------------------------------------
// Parallel start-flag dtype detection: bad[0]=not-int32, bad[1]=not-f32.
// ---------------------------------------------------------------------------
__global__ void detect_start_par(const unsigned int* __restrict__ s,
                                 int* __restrict__ bad) {
  const unsigned int w = s[blockIdx.x * blockDim.x + threadIdx.x];
  const unsigned int b0 = w & 255u, b1 = (w >> 8) & 255u,
                     b2 = (w >> 16) & 255u, b3 = (w >> 24) & 255u;
  const int bi = (b1 | b2 | b3) != 0;
  const int bf = (b0 != 0) || (b1 != 0) ||
                 (b2 != 0 && b2 != 0x80u) || (b3 != 0 && b3 != 0x3fu);
  if (__any(bi) && (threadIdx.x & 63) == 0) atomicOr(&bad[0], 1);
  if (__any(bf) && (threadIdx.x & 63) == 0) atomicOr(&bad[1], 1);
}

// ---------------------------------------------------------------------------
// f32 -> f16 conversion, vectorized.
// ---------------------------------------------------------------------------
__global__ void conv_f16(const float* __restrict__ in, _Float16* __restrict__ out,
                         const int n) {
  const int i = (blockIdx.x * blockDim.x + threadIdx.x) * 8;
  if (i + 7 >= n) return;
  const float4 a = *(const float4*)&in[i];
  const float4 b = *(const float4*)&in[i + 4];
  f16x8 v;
  v[0] = (_Float16)a.x; v[1] = (_Float16)a.y; v[2] = (_Float16)a.z; v[3] = (_Float16)a.w;
  v[4] = (_Float16)b.x; v[5] = (_Float16)b.y; v[6] = (_Float16)b.z; v[7] = (_Float16)b.w;
  *(f16x8*)&out[i] = v;
}

__global__ void conv_w8(const float* p0, const float* p1, const float* p2,
                        const float* p3, const float* p4, const float* p5,
                        const float* p6, const float* p7,
                        _Float16* __restrict__ out) {
  const int seg = blockIdx.y;
  const float* p;
  switch (seg) {
    case 0: p = p0; break; case 1: p = p1; break;
    case 2: p = p2; break; case 3: p = p3; break;
    case 4: p = p4; break; case 5: p = p5; break;
    case 6: p = p6; break; default: p = p7; break;
  }
  const int i = (blockIdx.x * blockDim.x + threadIdx.x) * 8;
  const float4 a = *(const float4*)&p[i];
  const float4 b = *(const float4*)&p[i + 4];
  f16x8 v;
  v[0] = (_Float16)a.x; v[1] = (_Float16)a.y; v[2] = (_Float16)a.z; v[3] = (_Float16)a.w;
  v[4] = (_Float16)b.x; v[5] = (_Float16)b.y; v[6] = (_Float16)b.z; v[7] = (_Float16)b.w;
  *(f16x8*)&out[(size_t)seg * 65536 + i] = v;
}

// ---------------------------------------------------------------------------
// Pre-swizzle Uf/Uh (both layers) into per-lane MFMA fragment order, fp16.
// ---------------------------------------------------------------------------
__global__ void swz_w(const float* __restrict__ Uf, const float* __restrict__ Uh,
                      _Float16* __restrict__ outp) {
  const int gid  = blockIdx.x * 256 + threadIdx.x;   // 32768 total
  const int lane = gid & 63;
  const int w    = (gid >> 6) & 7;
  const int f    = (gid >> 9) & 15;
  const int mat  = (gid >> 13) & 1;
  const int l    = gid >> 14;
  const int fr = lane & 15, fq = lane >> 4;
  const int tile = f >> 3, kc = f & 7;
  const int nrow = (w * 2 + tile) * 16 + fr;
  const int kb   = kc * 32 + fq * 8;
  const float* src = (mat ? Uh : Uf) + (size_t)l * 65536 + nrow * 256 + kb;
  const float4 a = *(const float4*)src;
  const float4 b = *(const float4*)(src + 4);
  f16x8 v;
  v[0] = (_Float16)a.x; v[1] = (_Float16)a.y; v[2] = (_Float16)a.z; v[3] = (_Float16)a.w;
  v[4] = (_Float16)b.x; v[5] = (_Float16)b.y; v[6] = (_Float16)b.z; v[7] = (_Float16)b.w;
  *(f16x8*)&outp[(size_t)gid * 8] = v;
}

// ---------------------------------------------------------------------------
// FUSED boundary GEMM (R16 k-loop structure) with b-grouped block rows:
// block bid covers rows r_l = t_l*8 + b  (t = bid*8 + t_l, t_l,b in [0,8)).
// Dual-output path stores to mat-plane P-layout via LDS EP repack:
//   granule g(t,b,wv,fqs) = slot(t)*512 + wv*64 + fqs*16 + grp(t)*8 + b
//   element (n) -> wv=n>>5, half=(n>>4)&1, fqs=(n>>2)&3, js=n&3
//   xP[mat*PLANE + g*8 + half*4 + js]
// Store phase emits 128B-contiguous runs (8 b-lanes). Scan reads 2x fully
// dense 16B/lane. C32 (final) path unchanged except row mapping.
// ---------------------------------------------------------------------------
__global__ __launch_bounds__(256, 2) void gemm_fused(
    const _Float16* __restrict__ A,
    const _Float16* __restrict__ W1, const float* __restrict__ b1, const int act1,
    const _Float16* __restrict__ Wa, const float* __restrict__ ba,
    const _Float16* __restrict__ Wb, const float* __restrict__ bb,
    _Float16* __restrict__ xP,
    float* __restrict__ C32) {
  __shared__ __align__(16) char smem[65536];
  char* Amid = smem;                 // 32KB: A tile, then mid (swizzled)
  char* stg  = smem + 32768;         // 2 x 16KB W double-buffer; EP reuse

  const int tid  = threadIdx.x;
  const int wave = tid >> 6, lane = tid & 63;
  const int wm = wave >> 1, wn = wave & 1;
  const int bid = blockIdx.x;
  const int lrow  = tid >> 2;        // 0..63
  const int lcol8 = (tid & 3) * 8;
  const int fr = lane & 15;
  const int fq = lane >> 4;

  // block-local row -> global A/C row: r_l = t_l*8 + b
  auto grow = [&](int r_l) -> size_t {
    return (size_t)(r_l & 7) * TT + (size_t)bid * 8 + (r_l >> 3);
  };

  auto ldswz = [&](int row, int colbyte) -> const f16x8* {
    return (const f16x8*)(Amid + row * 512 + (colbyte ^ ((row & 15) << 4)));
  };

  // ---- stage A once (swizzled source -> linear dest) ----
#pragma unroll
  for (int it = 0; it < 8; it++) {
    const int o   = (it * 256 + tid) * 16;
    const int row = o >> 9;
    const int cb  = (o & 511) ^ ((row & 15) << 4);
    gl_lds16(&A[grow(row) * HD + (cb >> 1)], Amid + o);
  }

  auto STW = [&](const _Float16* W, int kk, int b2) {  // 16KB tile, 4 ld/thr
    const int k0 = kk * 32;
#pragma unroll
    for (int is = 0; is < 4; is++)
      gl_lds16(&W[(size_t)(is * 64 + lrow) * HD + k0 + lcol8],
               stg + b2 * 16384 + is * 4096 + wave * 1024);
  };

  // ================= phase A: mid = act1(A @ W1^T + b1) =================
  {
    f32x4 acc[2][8];
#pragma unroll
    for (int i = 0; i < 2; i++)
#pragma unroll
      for (int j = 0; j < 8; j++) acc[i][j] = (f32x4){0.f, 0.f, 0.f, 0.f};

    STW(W1, 0, 0);
#pragma unroll
    for (int k = 0; k < 8; k++) {
      const int cur = k & 1;
      if (k < 7) {
        STW(W1, k + 1, cur ^ 1);
        asm volatile("s_waitcnt vmcnt(4)" ::: "memory");
      } else {
        asm volatile("s_waitcnt vmcnt(0)" ::: "memory");
      }
      gbar();
      const _Float16* Ws = (const _Float16*)(stg + cur * 16384);
      f16x8 af[2], bf[8];
#pragma unroll
      for (int mi = 0; mi < 2; mi++)
        af[mi] = *ldswz(wm * 32 + mi * 16 + fr, k * 64 + fq * 16);
#pragma unroll
      for (int ni = 0; ni < 8; ni++)
        bf[ni] = *(const f16x8*)(Ws + (wn * 128 + ni * 16 + fr) * 32 + fq * 8);
#pragma unroll
      for (int mi = 0; mi < 2; mi++)
#pragma unroll
        for (int ni = 0; ni < 8; ni++)
          acc[mi][ni] = __builtin_amdgcn_mfma_f32_16x16x32_f16(af[mi], bf[ni],
                                                               acc[mi][ni], 0, 0, 0);
      asm volatile("s_waitcnt lgkmcnt(0)" ::: "memory");
      gbar();
    }
    __syncthreads();   // all waves done reading A
    // epilogue: bias (+leaky) -> fp16 -> mid (overlays A, same swizzle)
#pragma unroll
    for (int mi = 0; mi < 2; mi++)
#pragma unroll
      for (int ni = 0; ni < 8; ni++) {
        const float bvv = b1[wn * 128 + ni * 16 + fr];
#pragma unroll
        for (int j = 0; j < 4; j++) {
          float v = acc[mi][ni][j] + bvv;
          if (act1 == 1) v = (v > 0.f) ? v : 0.01f * v;
          const int row = wm * 32 + mi * 16 + fq * 4 + j;
          const int cb  = ((wn * 128 + ni * 16 + fr) * 2) ^ ((row & 15) << 4);
          *(_Float16*)(Amid + row * 512 + cb) = (_Float16)v;
        }
      }
  }
  __syncthreads();  // mid complete & visible

  // ============== phase B: C = mid @ Wm^T + bm, per mat ==============
  const int nmat = (Wb != nullptr) ? 2 : 1;
  for (int mat = 0; mat < nmat; mat++) {
    const _Float16* W2 = mat ? Wb : Wa;
    const float* b2p   = mat ? bb : ba;

    f32x4 acc[2][8];
#pragma unroll
    for (int i = 0; i < 2; i++)
#pragma unroll
      for (int j = 0; j < 8; j++) acc[i][j] = (f32x4){0.f, 0.f, 0.f, 0.f};

    STW(W2, 0, 0);
#pragma unroll
    for (int k = 0; k < 8; k++) {
      const int cur = k & 1;
      if (k < 7) {
        STW(W2, k + 1, cur ^ 1);
        asm volatile("s_waitcnt vmcnt(4)" ::: "memory");
      } else {
        asm volatile("s_waitcnt vmcnt(0)" ::: "memory");
      }
      gbar();
      const _Float16* Ws = (const _Float16*)(stg + cur * 16384);
      f16x8 af[2], bf[8];
#pragma unroll
      for (int mi = 0; mi < 2; mi++)
        af[mi] = *ldswz(wm * 32 + mi * 16 + fr, k * 64 + fq * 16);
#pragma unroll
      for (int ni = 0; ni < 8; ni++)
        bf[ni] = *(const f16x8*)(Ws + (wn * 128 + ni * 16 + fr) * 32 + fq * 8);
#pragma unroll
      for (int mi = 0; mi < 2; mi++)
#pragma unroll
        for (int ni = 0; ni < 8; ni++)
          acc[mi][ni] = __builtin_amdgcn_mfma_f32_16x16x32_f16(af[mi], bf[ni],
                                                               acc[mi][ni], 0, 0, 0);
      asm volatile("s_waitcnt lgkmcnt(0)" ::: "memory");
      gbar();
    }

    if (C32 != nullptr) {
      // final output: fp32 direct scatter (row-mapped)
#pragma unroll
      for (int mi = 0; mi < 2; mi++)
#pragma unroll
        for (int ni = 0; ni < 8; ni++) {
          const float bvv = b2p[wn * 128 + ni * 16 + fr];
#pragma unroll
          for (int j = 0; j < 4; j++) {
            const int r_l = wm * 32 + mi * 16 + fq * 4 + j;
            C32[grow(r_l) * HD + wn * 128 + ni * 16 + fr] = acc[mi][ni][j] + bvv;
          }
        }
    } else {
      // ---- EP repack (stg reused; k-loop fully drained by last gbar) ----
      _Float16* EPh = (_Float16*)stg;   // [64 rows][256] f16, XOR'd 16B units
#pragma unroll
      for (int mi = 0; mi < 2; mi++)
#pragma unroll
        for (int ni = 0; ni < 8; ni++) {
          const int n   = wn * 128 + ni * 16 + fr;
          const float bvv = b2p[n];
          const int wv   = n >> 5;
          const int half = (n >> 4) & 1;
          const int fqs  = (n >> 2) & 3;
          const int js   = n & 3;
#pragma unroll
          for (int j = 0; j < 4; j++) {
            const int r_l = wm * 32 + mi * 16 + fq * 4 + j;
            const int u16 = ((wv << 2) | fqs) ^ (r_l & 7);
            EPh[r_l * 256 + u16 * 8 + half * 4 + js] =
                (_Float16)(acc[mi][ni][j] + bvv);
          }
        }
      __syncthreads();
      // ---- coalesced store phase: 128B-contiguous runs across b-lanes ----
      _Float16* xPm = xP + (size_t)mat * PLANE;
      {
        const int wv  = tid >> 5;
        const int fqs = (tid >> 3) & 3;
        const int bb2 = tid & 7;
#pragma unroll
        for (int it = 0; it < 8; it++) {
          const int r_l = it * 8 + bb2;
          const int u16 = ((wv << 2) | fqs) ^ bb2;
          const f16x8 v = *(const f16x8*)&EPh[r_l * 256 + u16 * 8];
          const int t    = bid * 8 + it;
          const int slot = ((t >> 5) << 4) | (t & 15);
          const int grp  = (t >> 4) & 1;
          const size_t g = (size_t)slot * 512 + wv * 64 + fqs * 16 + grp * 8 + bb2;
          *(f16x8*)&xPm[g * 8] = v;
        }
      }
      __syncthreads();  // EP(=stg) reusable for next mat's STW
    }
  }
}

// ---------------------------------------------------------------------------
// MGU scan — R19 structure (P-layout inputs), mat-plane split: per step two
// FULLY coalesced 16B/lane loads (lane index == granule offset).
// ---------------------------------------------------------------------------
__global__ __launch_bounds__(512) void scan_mgu(
    const _Float16* __restrict__ xP,
    const void* __restrict__ startp, const int* __restrict__ badf,
    const float* __restrict__ h0l,
    const _Float16* __restrict__ wfrag,
    _Float16* __restrict__ z, float* __restrict__ hfin,
    _Float16* __restrict__ dumpz) {
  const int tid  = threadIdx.x;
  const int wave = tid >> 6;
  const int lane = tid & 63;
  const int fr   = lane & 15;      // MFMA col / frag row
  const int fq   = lane >> 4;      // 0..3
  const int col  = fr;
  const int b    = col & 7;
  const int grp  = col >> 3;       // 0 = half-chunk A, 1 = B
  const int base = blockIdx.x * (2 * HC);
  const int t0c  = base + grp * HC;
  const int mode = (!badf[0]) ? 1 : (!badf[1] ? 2 : 0);

  __shared__ __align__(16) char hbuf[8192];  // frag layout [kc][krow][col][8]
  __shared__ __align__(16) char gbuf[8192];
  __shared__ int rb[16];

  _Float16* dp0 = dumpz + ((size_t)blockIdx.x * 512 + tid) * 16;

  auto flag = [&](int bb, int t) -> int {
    const int idx = bb * TT + t;
    if (mode == 1) return ((const int*)startp)[idx] != 0;
    if (mode == 2) return ((const float*)startp)[idx] != 0.0f;
    return ((const uint8_t*)startp)[idx] != 0;
  };
  auto ldfrag = [&](const char* buf, int kc) -> f16x8 {
    int off = kc * 1024 + fq * 256 + fr * 16;
    off ^= ((off >> 8) & 1) << 4;
    return *(const f16x8*)(buf + off);
  };
  auto stfrag = [&](char* buf, int nb, const float4 v) {
    int off = ((nb >> 5) * 1024) + (((nb >> 3) & 3) * 256) + col * 16 + (nb & 7) * 2;
    off ^= ((off >> 8) & 1) << 4;
    f16x4 p;
    p[0] = (_Float16)v.x; p[1] = (_Float16)v.y;
    p[2] = (_Float16)v.z; p[3] = (_Float16)v.w;
    *(f16x4*)(buf + off) = p;
  };
  // P-layout step load: two dense 16B/lane reads (xf plane, xh plane).
  auto ldx = [&](int tc, f16x4& xf0, f16x4& xf1, f16x4& xh0, f16x4& xh1) {
    const int slot = ((tc >> 5) << 4) | (tc & 15);
    const int gT   = (tc >> 4) & 1;
    const size_t g = (size_t)slot * 512 + wave * 64 + fq * 16 + gT * 8 + b;
    const f16x8 vf = *(const f16x8*)&xP[g * 8];
    const f16x8 vh = *(const f16x8*)&xP[PLANE + g * 8];
    xf0[0] = vf[0]; xf0[1] = vf[1]; xf0[2] = vf[2]; xf0[3] = vf[3];
    xf1[0] = vf[4]; xf1[1] = vf[5]; xf1[2] = vf[6]; xf1[3] = vf[7];
    xh0[0] = vh[0]; xh0[1] = vh[1]; xh0[2] = vh[2]; xh0[3] = vh[3];
    xh1[0] = vh[4]; xh1[1] = vh[5]; xh1[2] = vh[6]; xh1[3] = vh[7];
  };

  // ---- weight fragments: 32 coalesced dwordx4 per lane from swz buffer ----
  f16x8 auf[2][8], auh[2][8];
#pragma unroll
  for (int f = 0; f < 16; f++)
    auf[f >> 3][f & 7] =
        *(const f16x8*)&wfrag[((size_t)(f * 512) + wave * 64 + lane) * 8];
#pragma unroll
  for (int f = 0; f < 16; f++)
    auh[f >> 3][f & 7] =
        *(const f16x8*)&wfrag[((size_t)(8192 + f * 512) + wave * 64 + lane) * 8];

  // ---- per-column lookback: last reset <= t0c (or -1) ----
  if (tid < 16) rb[tid] = -1;
  __syncthreads();
  {
    const int cg  = tid >> 5;            // 16 groups x 32 threads
    const int l32 = tid & 31;
    const int t0g = base + (cg >> 3) * HC;
    const int bg  = cg & 7;
    for (int off = 0;; off += 32) {
      const int st = t0g - off - l32;
      if (st >= 0 && rb[cg] < 0 && flag(bg, st)) atomicMax(&rb[cg], st);
      __syncthreads();
      bool done = true;
#pragma unroll
      for (int c = 0; c < 16; c++) {
        const int tc = base + (c >> 3) * HC;
        if (rb[c] < 0 && tc - off >= 0) done = false;
      }
      if (done) break;
      __syncthreads();
    }
  }
  __syncthreads();

  const int rbc    = rb[col];
  const int startc = max(rbc, 0);
  int Lmax = 0;
#pragma unroll
  for (int c = 0; c < 16; c++) {
    const int tc = base + (c >> 3) * HC;
    const int s  = max(rb[c], 0);
    Lmax = max(Lmax, tc - s);
  }

  const int nb0 = (wave * 2 + 0) * 16 + fq * 4;
  const int nb1 = (wave * 2 + 1) * 16 + fq * 4;

  // ---- init carry (registers, D-layout) ----
  float4 hinit0 = make_float4(0.f, 0.f, 0.f, 0.f), hinit1 = hinit0;
  if (rbc < 0) {
    hinit0 = *(const float4*)&h0l[b * HD + nb0];
    hinit1 = *(const float4*)&h0l[b * HD + nb1];
  }
  float4 hr0 = hinit0, hr1 = hinit1;
  stfrag(hbuf, nb0, hr0);
  stfrag(hbuf, nb1, hr1);
  __syncthreads();

  // ---- prefetch first step (P-layout + fold flag; unconditional-clamped) --
  int t = t0c - Lmax;
  int tcl = min(max(t, 0), TT - 1);
  f16x4 pxf0, pxf1, pxh0, pxh1;
  ldx(tcl, pxf0, pxf1, pxh0, pxh1);
  int fnext;
  {
    const int ftn = flag(b, min(max(t + 1, 0), TT - 1));
    fnext = (t + 1 < TT) ? ftn : 0;
  }

  for (int i = -Lmax; i < HC; i++) {
    t = t0c + i;
    f32x4 cf0 = {(float)pxf0[0], (float)pxf0[1], (float)pxf0[2], (float)pxf0[3]};
    f32x4 cf1 = {(float)pxf1[0], (float)pxf1[1], (float)pxf1[2], (float)pxf1[3]};
    f32x4 ch0 = {(float)pxh0[0], (float)pxh0[1], (float)pxh0[2], (float)pxh0[3]};
    f32x4 ch1 = {(float)pxh1[0], (float)pxh1[1], (float)pxh1[2], (float)pxh1[3]};

    const int fcur = fnext;                      // flag(b, t+1)
    const int tn = min(max(t + 1, 0), TT - 1);
    ldx(tn, pxf0, pxf1, pxh0, pxh1);
    {
      const int ftn = flag(b, min(max(t + 2, 0), TT - 1));
      fnext = (t + 2 < TT) ? ftn : 0;
    }

    // carry-fold selector for next step: 2=freeze to init, 1=zero, 0=keep
    int stn = 0;
    if (t + 1 <= startc) stn = 2;
    else if (fcur) stn = 1;

    // matvec1: pre_f = Uf . h + xf
#pragma unroll
    for (int kc = 0; kc < 8; kc++) {
      const f16x8 bv = ldfrag(hbuf, kc);
      cf0 = __builtin_amdgcn_mfma_f32_16x16x32_f16(auf[0][kc], bv, cf0, 0, 0, 0);
      cf1 = __builtin_amdgcn_mfma_f32_16x16x32_f16(auf[1][kc], bv, cf1, 0, 0, 0);
    }
    // sigmoid, g = f*h
    f32x4 fv0, fv1;
    float4 g0, g1;
#pragma unroll
    for (int r = 0; r < 4; r++) {
      const float f0 = 1.f / (1.f + __expf(-cf0[r]));
      const float f1 = 1.f / (1.f + __expf(-cf1[r]));
      fv0[r] = f0; fv1[r] = f1;
      (&g0.x)[r] = f0 * (&hr0.x)[r];
      (&g1.x)[r] = f1 * (&hr1.x)[r];
    }
    stfrag(gbuf, nb0, g0);
    stfrag(gbuf, nb1, g1);
    ldsbar();

    // matvec2: pre_h = Uh . (f*h) + xh
#pragma unroll
    for (int kc = 0; kc < 8; kc++) {
      const f16x8 bv = ldfrag(gbuf, kc);
      ch0 = __builtin_amdgcn_mfma_f32_16x16x32_f16(auh[0][kc], bv, ch0, 0, 0, 0);
      ch1 = __builtin_amdgcn_mfma_f32_16x16x32_f16(auh[1][kc], bv, ch1, 0, 0, 0);
    }
    // update
    float4 hn0, hn1;
    f16x4 zn0, zn1;
#pragma unroll
    for (int r = 0; r < 4; r++) {
      const float e0 = __expf(2.f * ch0[r]);
      const float e1 = __expf(2.f * ch1[r]);
      const float hh0 = 1.f - 2.f / (e0 + 1.f);
      const float hh1 = 1.f - 2.f / (e1 + 1.f);
      (&hn0.x)[r] = (1.f - fv0[r]) * (&hr0.x)[r] + fv0[r] * hh0;
      (&hn1.x)[r] = (1.f - fv1[r]) * (&hr1.x)[r] + fv1[r] * hh1;
      zn0[r] = (_Float16)(&hn0.x)[r];
      zn1[r] = (_Float16)(&hn1.x)[r];
    }
    // z-store: ALWAYS issue; address selects real z vs per-thread dump slot.
    {
      const size_t tz = (size_t)b * TT + (size_t)max(t, 0);
      _Float16* zp0 = (i >= 0) ? &z[tz * HD + nb0] : dp0;
      _Float16* zp1 = (i >= 0) ? &z[tz * HD + nb1] : dp0 + 8;
      *(f16x4*)zp0 = zn0;
      *(f16x4*)zp1 = zn1;
    }
    // fold
    hr0 = (stn == 2) ? hinit0 : (stn == 1 ? make_float4(0.f, 0.f, 0.f, 0.f) : hn0);
    hr1 = (stn == 2) ? hinit1 : (stn == 1 ? make_float4(0.f, 0.f, 0.f, 0.f) : hn1);
    stfrag(hbuf, nb0, hr0);
    stfrag(hbuf, nb1, hr1);
    ldsbar();
  }

  // hfin: after the final step's fold (fcur=0, stn=0 at t=TT-1), hr == hn(TT-1)
  if (t0c + HC == TT) {
    *(float4*)&hfin[b * HD + nb0] = hr0;
    *(float4*)&hfin[b * HD + nb1] = hr1;
  }
}

// ---------------------------------------------------------------------------
extern "C" void kernel_launch(void* const* d_in, const int* in_sizes, int n_in,
                              void* d_out, int out_size, void* d_ws, size_t ws_size,
                              hipStream_t stream) {
  const float* emb    = (const float*)d_in[0];
  const void*  startp = d_in[1];
  const float* h0     = (const float*)d_in[2];
  const float* min_w  = (const float*)d_in[3];
  const float* min_b  = (const float*)d_in[4];
  const float* mout_w = (const float*)d_in[5];
  const float* mout_b = (const float*)d_in[6];
  const float* Wf_w   = (const float*)d_in[7];
  const float* Wf_b   = (const float*)d_in[8];
  const float* Wh_w   = (const float*)d_in[9];
  const float* Wh_b   = (const float*)d_in[10];
  const float* Uf_w   = (const float*)d_in[11];
  const float* Uh_w   = (const float*)d_in[12];
  const float* ff_w   = (const float*)d_in[13];
  const float* ff_b   = (const float*)d_in[14];

  float* out = (float*)d_out;
  char*  ws  = (char*)d_ws;
  int*   bad = (int*)ws;
  _Float16* w16  = (_Float16*)(ws + 1024);                         // 1 MB
  _Float16* uswz = (_Float16*)(ws + 1024 + 1048576);               // 512 KB
  _Float16* dump = (_Float16*)(ws + 1024 + 1048576 + 524288);      // 4 MB
  _Float16* bufE = (_Float16*)(ws + 1024 + 1048576 + 524288 + 4194304);  // 32 MB
  _Float16* bufA = bufE + (size_t)RTOT * HD;                        // 32 MB (z)
  _Float16* xP   = bufA + (size_t)RTOT * HD;                        // 64 MB
  float* hfin = out + (size_t)RTOT * HD;
  const size_t WO = (size_t)HD * HD;

  _Float16* w_min = w16;
  _Float16* w_out = w16 + 1 * WO;
  _Float16* w_f0  = w16 + 2 * WO;
  _Float16* w_f1  = w16 + 3 * WO;
  _Float16* w_h0  = w16 + 4 * WO;
  _Float16* w_h1  = w16 + 5 * WO;
  _Float16* w_ff0 = w16 + 6 * WO;
  _Float16* w_ff1 = w16 + 7 * WO;

  hipMemsetAsync(bad, 0, 16, stream);
  detect_start_par<<<64, 256, 0, stream>>>((const unsigned int*)startp, bad);
  conv_f16<<<RTOT * HD / 2048, 256, 0, stream>>>(emb, bufE, RTOT * HD);
  conv_w8<<<dim3(32, 8), 256, 0, stream>>>(min_w, mout_w, Wf_w, Wf_w + WO,
                                           Wh_w, Wh_w + WO, ff_w, ff_w + WO, w16);
  swz_w<<<128, 256, 0, stream>>>(Uf_w, Uh_w, uswz);

  // fused0: x0 = emb@min (internal) -> xP (xf plane, xh plane)
  gemm_fused<<<TT / 8, 256, 0, stream>>>(bufE, w_min, min_b, 0,
                                         w_f0, Wf_b, w_h0, Wh_b,
                                         xP, nullptr);
  scan_mgu<<<NPAIR, 512, 0, stream>>>(xP, startp, bad, h0,
                                      uswz, bufA, hfin, dump);
  // fused1: x1 = leaky(z0@ff0) (internal) -> xP
  gemm_fused<<<TT / 8, 256, 0, stream>>>(bufA, w_ff0, ff_b, 1,
                                         w_f1, Wf_b + HD, w_h1, Wh_b + HD,
                                         xP, nullptr);
  scan_mgu<<<NPAIR, 512, 0, stream>>>(xP, startp, bad, h0 + BATCH * HD,
                                      uswz + (size_t)16384 * 8, bufA,
                                      hfin + BATCH * HD, dump);
  // fused2: x2 = leaky(z1@ff1) (internal) -> out = x2@mout+b (fp32)
  gemm_fused<<<TT / 8, 256, 0, stream>>>(bufA, w_ff1, ff_b + HD, 1,
                                         w_out, mout_b, nullptr, nullptr,
                                         nullptr, out);
}

// Round 21
// 320.297 us; speedup vs baseline: 1.2693x; 1.0057x over previous
//
#include <hip/hip_runtime.h>
#include <hip/hip_fp16.h>
#include <cstdint>
#include <cstddef>

#define BATCH 8
#define TT 8192
#define HD 256
#define RTOT (BATCH * TT)   // 65536
#define HC 16               // half-chunk length
#define NPAIR (TT / (2 * HC)) // 256 workgroups, each owns 2 half-chunks
#define PLANE ((size_t)TT * 2048)  // f16 elems per xP mat-plane (32 MB)

typedef __attribute__((ext_vector_type(4))) float    f32x4;
typedef __attribute__((ext_vector_type(8))) _Float16 f16x8;
typedef __attribute__((ext_vector_type(4))) _Float16 f16x4;

typedef __attribute__((address_space(1))) const void gvoid_t;
typedef __attribute__((address_space(3))) void lvoid_t;

__device__ __forceinline__ void gl_lds16(const void* g, void* l) {
  __builtin_amdgcn_global_load_lds((gvoid_t*)g, (lvoid_t*)l, 16, 0, 0);
}

// LDS-only barrier, DS-masked fence (R12-exact; scan only).
__device__ __forceinline__ void ldsbar() {
  asm volatile("s_waitcnt lgkmcnt(0)" ::: "memory");
  __builtin_amdgcn_s_barrier();
  __builtin_amdgcn_sched_barrier(0x7F);
}

// Fenced barrier for the GEMM k-loop (R11/R13-validated pattern).
__device__ __forceinline__ void gbar() {
  __builtin_amdgcn_s_barrier();
  __builtin_amdgcn_sched_barrier(0);
  asm volatile("" ::: "memory");
}

// ---------------------------------------------------------------------------
// Parallel start-flag dtype detection: bad[0]=not-int32, bad[1]=not-f32.
// ---------------------------------------------------------------------------
__global__ void detect_start_par(const unsigned int* __restrict__ s,
                                 int* __restrict__ bad) {
  const unsigned int w = s[blockIdx.x * blockDim.x + threadIdx.x];
  const unsigned int b0 = w & 255u, b1 = (w >> 8) & 255u,
                     b2 = (w >> 16) & 255u, b3 = (w >> 24) & 255u;
  const int bi = (b1 | b2 | b3) != 0;
  const int bf = (b0 != 0) || (b1 != 0) ||
                 (b2 != 0 && b2 != 0x80u) || (b3 != 0 && b3 != 0x3fu);
  if (__any(bi) && (threadIdx.x & 63) == 0) atomicOr(&bad[0], 1);
  if (__any(bf) && (threadIdx.x & 63) == 0) atomicOr(&bad[1], 1);
}

// ---------------------------------------------------------------------------
// f32 -> f16 conversion, vectorized.
// ---------------------------------------------------------------------------
__global__ void conv_f16(const float* __restrict__ in, _Float16* __restrict__ out,
                         const int n) {
  const int i = (blockIdx.x * blockDim.x + threadIdx.x) * 8;
  if (i + 7 >= n) return;
  const float4 a = *(const float4*)&in[i];
  const float4 b = *(const float4*)&in[i + 4];
  f16x8 v;
  v[0] = (_Float16)a.x; v[1] = (_Float16)a.y; v[2] = (_Float16)a.z; v[3] = (_Float16)a.w;
  v[4] = (_Float16)b.x; v[5] = (_Float16)b.y; v[6] = (_Float16)b.z; v[7] = (_Float16)b.w;
  *(f16x8*)&out[i] = v;
}

__global__ void conv_w8(const float* p0, const float* p1, const float* p2,
                        const float* p3, const float* p4, const float* p5,
                        const float* p6, const float* p7,
                        _Float16* __restrict__ out) {
  const int seg = blockIdx.y;
  const float* p;
  switch (seg) {
    case 0: p = p0; break; case 1: p = p1; break;
    case 2: p = p2; break; case 3: p = p3; break;
    case 4: p = p4; break; case 5: p = p5; break;
    case 6: p = p6; break; default: p = p7; break;
  }
  const int i = (blockIdx.x * blockDim.x + threadIdx.x) * 8;
  const float4 a = *(const float4*)&p[i];
  const float4 b = *(const float4*)&p[i + 4];
  f16x8 v;
  v[0] = (_Float16)a.x; v[1] = (_Float16)a.y; v[2] = (_Float16)a.z; v[3] = (_Float16)a.w;
  v[4] = (_Float16)b.x; v[5] = (_Float16)b.y; v[6] = (_Float16)b.z; v[7] = (_Float16)b.w;
  *(f16x8*)&out[(size_t)seg * 65536 + i] = v;
}

// ---------------------------------------------------------------------------
// Pre-swizzle Uf/Uh (both layers) into per-lane MFMA fragment order, fp16.
// ---------------------------------------------------------------------------
__global__ void swz_w(const float* __restrict__ Uf, const float* __restrict__ Uh,
                      _Float16* __restrict__ outp) {
  const int gid  = blockIdx.x * 256 + threadIdx.x;   // 32768 total
  const int lane = gid & 63;
  const int w    = (gid >> 6) & 7;
  const int f    = (gid >> 9) & 15;
  const int mat  = (gid >> 13) & 1;
  const int l    = gid >> 14;
  const int fr = lane & 15, fq = lane >> 4;
  const int tile = f >> 3, kc = f & 7;
  const int nrow = (w * 2 + tile) * 16 + fr;
  const int kb   = kc * 32 + fq * 8;
  const float* src = (mat ? Uh : Uf) + (size_t)l * 65536 + nrow * 256 + kb;
  const float4 a = *(const float4*)src;
  const float4 b = *(const float4*)(src + 4);
  f16x8 v;
  v[0] = (_Float16)a.x; v[1] = (_Float16)a.y; v[2] = (_Float16)a.z; v[3] = (_Float16)a.w;
  v[4] = (_Float16)b.x; v[5] = (_Float16)b.y; v[6] = (_Float16)b.z; v[7] = (_Float16)b.w;
  *(f16x8*)&outp[(size_t)gid * 8] = v;
}

// ---------------------------------------------------------------------------
// FUSED boundary GEMM (R20 structure + amode): block bid covers rows
// r_l = t_l*8 + b (t = bid*8 + t_l). A-row mapping:
//   amode=0: A is (b,t)-row-major (emb path)   -> grow(r_l)
//   amode=1: A is zT layout [(t*8+b)][HD]      -> bid*64 + r_l  (contiguous!)
// Dual-output path stores mat-plane P-layout via LDS EP repack (R20-exact).
// C32 (final) path writes original (b,t)-row-major via grow().
// ---------------------------------------------------------------------------
__global__ __launch_bounds__(256, 2) void gemm_fused(
    const _Float16* __restrict__ A, const int amode,
    const _Float16* __restrict__ W1, const float* __restrict__ b1, const int act1,
    const _Float16* __restrict__ Wa, const float* __restrict__ ba,
    const _Float16* __restrict__ Wb, const float* __restrict__ bb,
    _Float16* __restrict__ xP,
    float* __restrict__ C32) {
  __shared__ __align__(16) char smem[65536];
  char* Amid = smem;                 // 32KB: A tile, then mid (swizzled)
  char* stg  = smem + 32768;         // 2 x 16KB W double-buffer; EP reuse

  const int tid  = threadIdx.x;
  const int wave = tid >> 6, lane = tid & 63;
  const int wm = wave >> 1, wn = wave & 1;
  const int bid = blockIdx.x;
  const int lrow  = tid >> 2;        // 0..63
  const int lcol8 = (tid & 3) * 8;
  const int fr = lane & 15;
  const int fq = lane >> 4;

  // block-local row -> global (b,t)-row-major row: r_l = t_l*8 + b
  auto grow = [&](int r_l) -> size_t {
    return (size_t)(r_l & 7) * TT + (size_t)bid * 8 + (r_l >> 3);
  };
  auto arow = [&](int r_l) -> size_t {
    return amode ? ((size_t)bid * 64 + r_l) : grow(r_l);
  };

  auto ldswz = [&](int row, int colbyte) -> const f16x8* {
    return (const f16x8*)(Amid + row * 512 + (colbyte ^ ((row & 15) << 4)));
  };

  // ---- stage A once (swizzled source -> linear dest) ----
#pragma unroll
  for (int it = 0; it < 8; it++) {
    const int o   = (it * 256 + tid) * 16;
    const int row = o >> 9;
    const int cb  = (o & 511) ^ ((row & 15) << 4);
    gl_lds16(&A[arow(row) * HD + (cb >> 1)], Amid + o);
  }

  auto STW = [&](const _Float16* W, int kk, int b2) {  // 16KB tile, 4 ld/thr
    const int k0 = kk * 32;
#pragma unroll
    for (int is = 0; is < 4; is++)
      gl_lds16(&W[(size_t)(is * 64 + lrow) * HD + k0 + lcol8],
               stg + b2 * 16384 + is * 4096 + wave * 1024);
  };

  // ================= phase A: mid = act1(A @ W1^T + b1) =================
  {
    f32x4 acc[2][8];
#pragma unroll
    for (int i = 0; i < 2; i++)
#pragma unroll
      for (int j = 0; j < 8; j++) acc[i][j] = (f32x4){0.f, 0.f, 0.f, 0.f};

    STW(W1, 0, 0);
#pragma unroll
    for (int k = 0; k < 8; k++) {
      const int cur = k & 1;
      if (k < 7) {
        STW(W1, k + 1, cur ^ 1);
        asm volatile("s_waitcnt vmcnt(4)" ::: "memory");
      } else {
        asm volatile("s_waitcnt vmcnt(0)" ::: "memory");
      }
      gbar();
      const _Float16* Ws = (const _Float16*)(stg + cur * 16384);
      f16x8 af[2], bf[8];
#pragma unroll
      for (int mi = 0; mi < 2; mi++)
        af[mi] = *ldswz(wm * 32 + mi * 16 + fr, k * 64 + fq * 16);
#pragma unroll
      for (int ni = 0; ni < 8; ni++)
        bf[ni] = *(const f16x8*)(Ws + (wn * 128 + ni * 16 + fr) * 32 + fq * 8);
#pragma unroll
      for (int mi = 0; mi < 2; mi++)
#pragma unroll
        for (int ni = 0; ni < 8; ni++)
          acc[mi][ni] = __builtin_amdgcn_mfma_f32_16x16x32_f16(af[mi], bf[ni],
                                                               acc[mi][ni], 0, 0, 0);
      asm volatile("s_waitcnt lgkmcnt(0)" ::: "memory");
      gbar();
    }
    __syncthreads();   // all waves done reading A
    // epilogue: bias (+leaky) -> fp16 -> mid (overlays A, same swizzle)
#pragma unroll
    for (int mi = 0; mi < 2; mi++)
#pragma unroll
      for (int ni = 0; ni < 8; ni++) {
        const float bvv = b1[wn * 128 + ni * 16 + fr];
#pragma unroll
        for (int j = 0; j < 4; j++) {
          float v = acc[mi][ni][j] + bvv;
          if (act1 == 1) v = (v > 0.f) ? v : 0.01f * v;
          const int row = wm * 32 + mi * 16 + fq * 4 + j;
          const int cb  = ((wn * 128 + ni * 16 + fr) * 2) ^ ((row & 15) << 4);
          *(_Float16*)(Amid + row * 512 + cb) = (_Float16)v;
        }
      }
  }
  __syncthreads();  // mid complete & visible

  // ============== phase B: C = mid @ Wm^T + bm, per mat ==============
  const int nmat = (Wb != nullptr) ? 2 : 1;
  for (int mat = 0; mat < nmat; mat++) {
    const _Float16* W2 = mat ? Wb : Wa;
    const float* b2p   = mat ? bb : ba;

    f32x4 acc[2][8];
#pragma unroll
    for (int i = 0; i < 2; i++)
#pragma unroll
      for (int j = 0; j < 8; j++) acc[i][j] = (f32x4){0.f, 0.f, 0.f, 0.f};

    STW(W2, 0, 0);
#pragma unroll
    for (int k = 0; k < 8; k++) {
      const int cur = k & 1;
      if (k < 7) {
        STW(W2, k + 1, cur ^ 1);
        asm volatile("s_waitcnt vmcnt(4)" ::: "memory");
      } else {
        asm volatile("s_waitcnt vmcnt(0)" ::: "memory");
      }
      gbar();
      const _Float16* Ws = (const _Float16*)(stg + cur * 16384);
      f16x8 af[2], bf[8];
#pragma unroll
      for (int mi = 0; mi < 2; mi++)
        af[mi] = *ldswz(wm * 32 + mi * 16 + fr, k * 64 + fq * 16);
#pragma unroll
      for (int ni = 0; ni < 8; ni++)
        bf[ni] = *(const f16x8*)(Ws + (wn * 128 + ni * 16 + fr) * 32 + fq * 8);
#pragma unroll
      for (int mi = 0; mi < 2; mi++)
#pragma unroll
        for (int ni = 0; ni < 8; ni++)
          acc[mi][ni] = __builtin_amdgcn_mfma_f32_16x16x32_f16(af[mi], bf[ni],
                                                               acc[mi][ni], 0, 0, 0);
      asm volatile("s_waitcnt lgkmcnt(0)" ::: "memory");
      gbar();
    }

    if (C32 != nullptr) {
      // final output: fp32 direct scatter to (b,t)-row-major (64B runs)
#pragma unroll
      for (int mi = 0; mi < 2; mi++)
#pragma unroll
        for (int ni = 0; ni < 8; ni++) {
          const float bvv = b2p[wn * 128 + ni * 16 + fr];
#pragma unroll
          for (int j = 0; j < 4; j++) {
            const int r_l = wm * 32 + mi * 16 + fq * 4 + j;
            C32[grow(r_l) * HD + wn * 128 + ni * 16 + fr] = acc[mi][ni][j] + bvv;
          }
        }
    } else {
      // ---- EP repack (stg reused; k-loop fully drained by last gbar) ----
      _Float16* EPh = (_Float16*)stg;   // [64 rows][256] f16, XOR'd 16B units
#pragma unroll
      for (int mi = 0; mi < 2; mi++)
#pragma unroll
        for (int ni = 0; ni < 8; ni++) {
          const int n   = wn * 128 + ni * 16 + fr;
          const float bvv = b2p[n];
          const int wv   = n >> 5;
          const int half = (n >> 4) & 1;
          const int fqs  = (n >> 2) & 3;
          const int js   = n & 3;
#pragma unroll
          for (int j = 0; j < 4; j++) {
            const int r_l = wm * 32 + mi * 16 + fq * 4 + j;
            const int u16 = ((wv << 2) | fqs) ^ (r_l & 7);
            EPh[r_l * 256 + u16 * 8 + half * 4 + js] =
                (_Float16)(acc[mi][ni][j] + bvv);
          }
        }
      __syncthreads();
      // ---- coalesced store phase: 128B-contiguous runs across b-lanes ----
      _Float16* xPm = xP + (size_t)mat * PLANE;
      {
        const int wv  = tid >> 5;
        const int fqs = (tid >> 3) & 3;
        const int bb2 = tid & 7;
#pragma unroll
        for (int it = 0; it < 8; it++) {
          const int r_l = it * 8 + bb2;
          const int u16 = ((wv << 2) | fqs) ^ bb2;
          const f16x8 v = *(const f16x8*)&EPh[r_l * 256 + u16 * 8];
          const int t    = bid * 8 + it;
          const int slot = ((t >> 5) << 4) | (t & 15);
          const int grp  = (t >> 4) & 1;
          const size_t g = (size_t)slot * 512 + wv * 64 + fqs * 16 + grp * 8 + bb2;
          *(f16x8*)&xPm[g * 8] = v;
        }
      }
      __syncthreads();  // EP(=stg) reusable for next mat's STW
    }
  }
}

// ---------------------------------------------------------------------------
// MGU scan — R20 structure; ONLY the z-store layout changed to zT
// ((t*8+b)-row-major): 8 b-lanes hit 8 consecutive 512B rows -> 32B-merged
// stores instead of 4MB-scattered 8B singles.
// ---------------------------------------------------------------------------
__global__ __launch_bounds__(512) void scan_mgu(
    const _Float16* __restrict__ xP,
    const void* __restrict__ startp, const int* __restrict__ badf,
    const float* __restrict__ h0l,
    const _Float16* __restrict__ wfrag,
    _Float16* __restrict__ z, float* __restrict__ hfin,
    _Float16* __restrict__ dumpz) {
  const int tid  = threadIdx.x;
  const int wave = tid >> 6;
  const int lane = tid & 63;
  const int fr   = lane & 15;      // MFMA col / frag row
  const int fq   = lane >> 4;      // 0..3
  const int col  = fr;
  const int b    = col & 7;
  const int grp  = col >> 3;       // 0 = half-chunk A, 1 = B
  const int base = blockIdx.x * (2 * HC);
  const int t0c  = base + grp * HC;
  const int mode = (!badf[0]) ? 1 : (!badf[1] ? 2 : 0);

  __shared__ __align__(16) char hbuf[8192];  // frag layout [kc][krow][col][8]
  __shared__ __align__(16) char gbuf[8192];
  __shared__ int rb[16];

  _Float16* dp0 = dumpz + ((size_t)blockIdx.x * 512 + tid) * 16;

  auto flag = [&](int bb, int t) -> int {
    const int idx = bb * TT + t;
    if (mode == 1) return ((const int*)startp)[idx] != 0;
    if (mode == 2) return ((const float*)startp)[idx] != 0.0f;
    return ((const uint8_t*)startp)[idx] != 0;
  };
  auto ldfrag = [&](const char* buf, int kc) -> f16x8 {
    int off = kc * 1024 + fq * 256 + fr * 16;
    off ^= ((off >> 8) & 1) << 4;
    return *(const f16x8*)(buf + off);
  };
  auto stfrag = [&](char* buf, int nb, const float4 v) {
    int off = ((nb >> 5) * 1024) + (((nb >> 3) & 3) * 256) + col * 16 + (nb & 7) * 2;
    off ^= ((off >> 8) & 1) << 4;
    f16x4 p;
    p[0] = (_Float16)v.x; p[1] = (_Float16)v.y;
    p[2] = (_Float16)v.z; p[3] = (_Float16)v.w;
    *(f16x4*)(buf + off) = p;
  };
  // P-layout step load: two dense 16B/lane reads (xf plane, xh plane).
  auto ldx = [&](int tc, f16x4& xf0, f16x4& xf1, f16x4& xh0, f16x4& xh1) {
    const int slot = ((tc >> 5) << 4) | (tc & 15);
    const int gT   = (tc >> 4) & 1;
    const size_t g = (size_t)slot * 512 + wave * 64 + fq * 16 + gT * 8 + b;
    const f16x8 vf = *(const f16x8*)&xP[g * 8];
    const f16x8 vh = *(const f16x8*)&xP[PLANE + g * 8];
    xf0[0] = vf[0]; xf0[1] = vf[1]; xf0[2] = vf[2]; xf0[3] = vf[3];
    xf1[0] = vf[4]; xf1[1] = vf[5]; xf1[2] = vf[6]; xf1[3] = vf[7];
    xh0[0] = vh[0]; xh0[1] = vh[1]; xh0[2] = vh[2]; xh0[3] = vh[3];
    xh1[0] = vh[4]; xh1[1] = vh[5]; xh1[2] = vh[6]; xh1[3] = vh[7];
  };

  // ---- weight fragments: 32 coalesced dwordx4 per lane from swz buffer ----
  f16x8 auf[2][8], auh[2][8];
#pragma unroll
  for (int f = 0; f < 16; f++)
    auf[f >> 3][f & 7] =
        *(const f16x8*)&wfrag[((size_t)(f * 512) + wave * 64 + lane) * 8];
#pragma unroll
  for (int f = 0; f < 16; f++)
    auh[f >> 3][f & 7] =
        *(const f16x8*)&wfrag[((size_t)(8192 + f * 512) + wave * 64 + lane) * 8];

  // ---- per-column lookback: last reset <= t0c (or -1) ----
  if (tid < 16) rb[tid] = -1;
  __syncthreads();
  {
    const int cg  = tid >> 5;            // 16 groups x 32 threads
    const int l32 = tid & 31;
    const int t0g = base + (cg >> 3) * HC;
    const int bg  = cg & 7;
    for (int off = 0;; off += 32) {
      const int st = t0g - off - l32;
      if (st >= 0 && rb[cg] < 0 && flag(bg, st)) atomicMax(&rb[cg], st);
      __syncthreads();
      bool done = true;
#pragma unroll
      for (int c = 0; c < 16; c++) {
        const int tc = base + (c >> 3) * HC;
        if (rb[c] < 0 && tc - off >= 0) done = false;
      }
      if (done) break;
      __syncthreads();
    }
  }
  __syncthreads();

  const int rbc    = rb[col];
  const int startc = max(rbc, 0);
  int Lmax = 0;
#pragma unroll
  for (int c = 0; c < 16; c++) {
    const int tc = base + (c >> 3) * HC;
    const int s  = max(rb[c], 0);
    Lmax = max(Lmax, tc - s);
  }

  const int nb0 = (wave * 2 + 0) * 16 + fq * 4;
  const int nb1 = (wave * 2 + 1) * 16 + fq * 4;

  // ---- init carry (registers, D-layout) ----
  float4 hinit0 = make_float4(0.f, 0.f, 0.f, 0.f), hinit1 = hinit0;
  if (rbc < 0) {
    hinit0 = *(const float4*)&h0l[b * HD + nb0];
    hinit1 = *(const float4*)&h0l[b * HD + nb1];
  }
  float4 hr0 = hinit0, hr1 = hinit1;
  stfrag(hbuf, nb0, hr0);
  stfrag(hbuf, nb1, hr1);
  __syncthreads();

  // ---- prefetch first step (P-layout + fold flag; unconditional-clamped) --
  int t = t0c - Lmax;
  int tcl = min(max(t, 0), TT - 1);
  f16x4 pxf0, pxf1, pxh0, pxh1;
  ldx(tcl, pxf0, pxf1, pxh0, pxh1);
  int fnext;
  {
    const int ftn = flag(b, min(max(t + 1, 0), TT - 1));
    fnext = (t + 1 < TT) ? ftn : 0;
  }

  for (int i = -Lmax; i < HC; i++) {
    t = t0c + i;
    f32x4 cf0 = {(float)pxf0[0], (float)pxf0[1], (float)pxf0[2], (float)pxf0[3]};
    f32x4 cf1 = {(float)pxf1[0], (float)pxf1[1], (float)pxf1[2], (float)pxf1[3]};
    f32x4 ch0 = {(float)pxh0[0], (float)pxh0[1], (float)pxh0[2], (float)pxh0[3]};
    f32x4 ch1 = {(float)pxh1[0], (float)pxh1[1], (float)pxh1[2], (float)pxh1[3]};

    const int fcur = fnext;                      // flag(b, t+1)
    const int tn = min(max(t + 1, 0), TT - 1);
    ldx(tn, pxf0, pxf1, pxh0, pxh1);
    {
      const int ftn = flag(b, min(max(t + 2, 0), TT - 1));
      fnext = (t + 2 < TT) ? ftn : 0;
    }

    // carry-fold selector for next step: 2=freeze to init, 1=zero, 0=keep
    int stn = 0;
    if (t + 1 <= startc) stn = 2;
    else if (fcur) stn = 1;

    // matvec1: pre_f = Uf . h + xf
#pragma unroll
    for (int kc = 0; kc < 8; kc++) {
      const f16x8 bv = ldfrag(hbuf, kc);
      cf0 = __builtin_amdgcn_mfma_f32_16x16x32_f16(auf[0][kc], bv, cf0, 0, 0, 0);
      cf1 = __builtin_amdgcn_mfma_f32_16x16x32_f16(auf[1][kc], bv, cf1, 0, 0, 0);
    }
    // sigmoid, g = f*h
    f32x4 fv0, fv1;
    float4 g0, g1;
#pragma unroll
    for (int r = 0; r < 4; r++) {
      const float f0 = 1.f / (1.f + __expf(-cf0[r]));
      const float f1 = 1.f / (1.f + __expf(-cf1[r]));
      fv0[r] = f0; fv1[r] = f1;
      (&g0.x)[r] = f0 * (&hr0.x)[r];
      (&g1.x)[r] = f1 * (&hr1.x)[r];
    }
    stfrag(gbuf, nb0, g0);
    stfrag(gbuf, nb1, g1);
    ldsbar();

    // matvec2: pre_h = Uh . (f*h) + xh
#pragma unroll
    for (int kc = 0; kc < 8; kc++) {
      const f16x8 bv = ldfrag(gbuf, kc);
      ch0 = __builtin_amdgcn_mfma_f32_16x16x32_f16(auh[0][kc], bv, ch0, 0, 0, 0);
      ch1 = __builtin_amdgcn_mfma_f32_16x16x32_f16(auh[1][kc], bv, ch1, 0, 0, 0);
    }
    // update
    float4 hn0, hn1;
    f16x4 zn0, zn1;
#pragma unroll
    for (int r = 0; r < 4; r++) {
      const float e0 = __expf(2.f * ch0[r]);
      const float e1 = __expf(2.f * ch1[r]);
      const float hh0 = 1.f - 2.f / (e0 + 1.f);
      const float hh1 = 1.f - 2.f / (e1 + 1.f);
      (&hn0.x)[r] = (1.f - fv0[r]) * (&hr0.x)[r] + fv0[r] * hh0;
      (&hn1.x)[r] = (1.f - fv1[r]) * (&hr1.x)[r] + fv1[r] * hh1;
      zn0[r] = (_Float16)(&hn0.x)[r];
      zn1[r] = (_Float16)(&hn1.x)[r];
    }
    // z-store (zT layout): ALWAYS issue; dump slot for lookback steps.
    {
      const size_t tz = (size_t)max(t, 0) * 8 + b;
      _Float16* zp0 = (i >= 0) ? &z[tz * HD + nb0] : dp0;
      _Float16* zp1 = (i >= 0) ? &z[tz * HD + nb1] : dp0 + 8;
      *(f16x4*)zp0 = zn0;
      *(f16x4*)zp1 = zn1;
    }
    // fold
    hr0 = (stn == 2) ? hinit0 : (stn == 1 ? make_float4(0.f, 0.f, 0.f, 0.f) : hn0);
    hr1 = (stn == 2) ? hinit1 : (stn == 1 ? make_float4(0.f, 0.f, 0.f, 0.f) : hn1);
    stfrag(hbuf, nb0, hr0);
    stfrag(hbuf, nb1, hr1);
    ldsbar();
  }

  // hfin: after the final step's fold (fcur=0, stn=0 at t=TT-1), hr == hn(TT-1)
  if (t0c + HC == TT) {
    *(float4*)&hfin[b * HD + nb0] = hr0;
    *(float4*)&hfin[b * HD + nb1] = hr1;
  }
}

// ---------------------------------------------------------------------------
extern "C" void kernel_launch(void* const* d_in, const int* in_sizes, int n_in,
                              void* d_out, int out_size, void* d_ws, size_t ws_size,
                              hipStream_t stream) {
  const float* emb    = (const float*)d_in[0];
  const void*  startp = d_in[1];
  const float* h0     = (const float*)d_in[2];
  const float* min_w  = (const float*)d_in[3];
  const float* min_b  = (const float*)d_in[4];
  const float* mout_w = (const float*)d_in[5];
  const float* mout_b = (const float*)d_in[6];
  const float* Wf_w   = (const float*)d_in[7];
  const float* Wf_b   = (const float*)d_in[8];
  const float* Wh_w   = (const float*)d_in[9];
  const float* Wh_b   = (const float*)d_in[10];
  const float* Uf_w   = (const float*)d_in[11];
  const float* Uh_w   = (const float*)d_in[12];
  const float* ff_w   = (const float*)d_in[13];
  const float* ff_b   = (const float*)d_in[14];

  float* out = (float*)d_out;
  char*  ws  = (char*)d_ws;
  int*   bad = (int*)ws;
  _Float16* w16  = (_Float16*)(ws + 1024);                         // 1 MB
  _Float16* uswz = (_Float16*)(ws + 1024 + 1048576);               // 512 KB
  _Float16* dump = (_Float16*)(ws + 1024 + 1048576 + 524288);      // 4 MB
  _Float16* bufE = (_Float16*)(ws + 1024 + 1048576 + 524288 + 4194304);  // 32 MB
  _Float16* bufA = bufE + (size_t)RTOT * HD;                        // 32 MB (zT)
  _Float16* xP   = bufA + (size_t)RTOT * HD;                        // 64 MB
  float* hfin = out + (size_t)RTOT * HD;
  const size_t WO = (size_t)HD * HD;

  _Float16* w_min = w16;
  _Float16* w_out = w16 + 1 * WO;
  _Float16* w_f0  = w16 + 2 * WO;
  _Float16* w_f1  = w16 + 3 * WO;
  _Float16* w_h0  = w16 + 4 * WO;
  _Float16* w_h1  = w16 + 5 * WO;
  _Float16* w_ff0 = w16 + 6 * WO;
  _Float16* w_ff1 = w16 + 7 * WO;

  hipMemsetAsync(bad, 0, 16, stream);
  detect_start_par<<<64, 256, 0, stream>>>((const unsigned int*)startp, bad);
  conv_f16<<<RTOT * HD / 2048, 256, 0, stream>>>(emb, bufE, RTOT * HD);
  conv_w8<<<dim3(32, 8), 256, 0, stream>>>(min_w, mout_w, Wf_w, Wf_w + WO,
                                           Wh_w, Wh_w + WO, ff_w, ff_w + WO, w16);
  swz_w<<<128, 256, 0, stream>>>(Uf_w, Uh_w, uswz);

  // fused0: x0 = emb@min (internal; A in (b,t) layout) -> xP planes
  gemm_fused<<<TT / 8, 256, 0, stream>>>(bufE, 0, w_min, min_b, 0,
                                         w_f0, Wf_b, w_h0, Wh_b,
                                         xP, nullptr);
  scan_mgu<<<NPAIR, 512, 0, stream>>>(xP, startp, bad, h0,
                                      uswz, bufA, hfin, dump);
  // fused1: x1 = leaky(z0@ff0) (A = zT layout) -> xP planes
  gemm_fused<<<TT / 8, 256, 0, stream>>>(bufA, 1, w_ff0, ff_b, 1,
                                         w_f1, Wf_b + HD, w_h1, Wh_b + HD,
                                         xP, nullptr);
  scan_mgu<<<NPAIR, 512, 0, stream>>>(xP, startp, bad, h0 + BATCH * HD,
                                      uswz + (size_t)16384 * 8, bufA,
                                      hfin + BATCH * HD, dump);
  // fused2: x2 = leaky(z1@ff1) (A = zT layout) -> out (fp32, (b,t) layout)
  gemm_fused<<<TT / 8, 256, 0, stream>>>(bufA, 1, w_ff1, ff_b + HD, 1,
                                         w_out, mout_b, nullptr, nullptr,
                                         nullptr, out);
}